// Round 1
// baseline (3240.061 us; speedup 1.0000x reference)
//
#include <hip/hip_runtime.h>

// BaseRNN B=64,S=512,H=E=512,L=2 — persistent kernel, R11.
// R10 recap: chain = drain -> flag store -> flag poll -> data load (~3 agent
// round trips/phase). R11 (full-ring path): FUSE freshness into the data.
// Ring is pre-poisoned with 0xFF...F (a float2 both-NaN pattern the kernel can
// never store: every stored value is a finite tanh output, 0, or a copy).
// Consumers poll the 8B data words directly until non-poison:
//   chain = producer store lands -> consumer poll hits it  (ONE hop).
// No flags, no vmcnt0 drain, no flag->data ordering (each 8B datum is
// individually self-announcing; 8B atomic store/load = no torn words).
// l0 free-runs (polls only its own peers); l1's l0-ahead check is implicit.
// Small-ring fallback (ws too small) keeps the proven R10 flag protocol.

#define BATCH 64
#define SEQ   512
#define HID   512
#define NTHR  256
#define CB    8
#define ROWS  32
#define SLOT  (BATCH * HID)     // floats per ring slot (128KB)

typedef unsigned int u32;
typedef unsigned long long u64;
#define POISON 0xFFFFFFFFFFFFFFFFull

__device__ __forceinline__ float dot4(const float4 a, const float4 b) {
  return a.x * b.x + a.y * b.y + a.z * b.z + a.w * b.w;
}
__device__ __forceinline__ float2 ld2(const double* p) {   // sc1 8B load
  const double d = __hip_atomic_load(p, __ATOMIC_RELAXED, __HIP_MEMORY_SCOPE_AGENT);
  return __builtin_bit_cast(float2, d);
}
__device__ __forceinline__ u64 ldu(const double* p) {      // sc1 8B load (raw)
  const double d = __hip_atomic_load(p, __ATOMIC_RELAXED, __HIP_MEMORY_SCOPE_AGENT);
  return __builtin_bit_cast(u64, d);
}
__device__ __forceinline__ void st2(double* p, float2 v) { // sc1 8B store
  __hip_atomic_store(p, __builtin_bit_cast(double, v),
                     __ATOMIC_RELAXED, __HIP_MEMORY_SCOPE_AGENT);
}
__device__ __forceinline__ float tanh_fast(float x) {
  const float a = fabsf(x);
  const float e = __expf(-2.0f * a);
  const float t = (1.0f - e) * __builtin_amdgcn_rcpf(1.0f + e);
  return copysignf(t, x);
}
#define WAIT_VM0() asm volatile("s_waitcnt vmcnt(0)" ::: "memory")

#define RSTEP(D, N)                                                   \
  {                                                                   \
    const bool hi = (lane & (D)) != 0;                                \
    _Pragma("unroll")                                                 \
    for (int a = 0; a < (N); ++a) {                                   \
      const float keep = hi ? v[a + (N)] : v[a];                      \
      const float send = hi ? v[a] : v[a + (N)];                      \
      v[a] = keep + __shfl_xor(send, (D));                            \
    }                                                                 \
  }

template <bool NP>  // NP = NaN-poll protocol (full 513-slot ring)
__global__ __launch_bounds__(NTHR, 1) void rnn_persistent(
    const int* __restrict__ x, const int* __restrict__ lengths,
    const float* __restrict__ emb,
    const float* __restrict__ W_ih, const float* __restrict__ W_hh,
    const float* __restrict__ b_ih, const float* __restrict__ b_hh,
    float* __restrict__ out,
    float* h0r, float* h1r, u32* F, int ring)
{
  __shared__ __align__(16) float Xa[CB][HID];        // 16KB
  __shared__ __align__(16) float Xb[CB][HID];        // 16KB
  __shared__ __align__(16) float Xpart[CB][ROWS][4]; // 4KB
  __shared__ int Lens[CB];

  const int wg    = blockIdx.x;
  const int tid   = threadIdx.x;
  const int dom   = wg & 7;
  const int q     = wg >> 3;
  const int layer = q >> 4;
  const int rg    = q & 15;
  const int bbase = dom * CB;
  const int jbase = rg * ROWS;
  const int tj    = tid >> 6;
  const int lane  = tid & 63;

  // flags (fallback protocol only): entry (dom,layer,rg) on its own 128B line
  u32* Fown = F + ((dom * 2 + layer) * 16 + rg) * 32;
  u32* F0   = F + ((dom * 2 + 0) * 16) * 32;   // + i*32
  u32* F1   = F + ((dom * 2 + 1) * 16) * 32;

  // ---- weights in registers: 8 j x (2 float4 k) x 2 mats = 128 VGPRs ----
  float4 wa[2][8], wb[2][8];
  {
    const float* WA = W_ih + layer * (HID * HID);
    const float* WB = W_hh + layer * (HID * HID);
    #pragma unroll
    for (int ji = 0; ji < 8; ++ji) {
      const int j = jbase + tj * 8 + ji;
      #pragma unroll
      for (int i = 0; i < 2; ++i) {
        const int k = i * 256 + 4 * lane;
        wa[i][ji] = *(const float4*)&WA[j * HID + k];
        wb[i][ji] = *(const float4*)&WB[j * HID + k];
      }
    }
  }
  if (tid < CB) Lens[tid] = lengths[bbase + tid];
  __syncthreads();
  int maxlen = Lens[0];
  #pragma unroll
  for (int i = 1; i < CB; ++i) maxlen = max(maxlen, Lens[i]);
  const int P     = maxlen;                       // 1..512
  const int pl0   = (P < SEQ) ? P : (SEQ - 1);    // l0's last active phase
  const int plast = layer ? P : pl0;
  int lm[4];                                      // group liveness bounds
  #pragma unroll
  for (int g = 0; g < 4; ++g) lm[g] = max(Lens[2 * g], Lens[2 * g + 1]);

  float4 bias4 = make_float4(0.f, 0.f, 0.f, 0.f);
  if (tid < 64) {
    const int jq = jbase + (tid & 7) * 4;
    bias4.x = b_ih[layer * HID + jq + 0] + b_hh[layer * HID + jq + 0];
    bias4.y = b_ih[layer * HID + jq + 1] + b_hh[layer * HID + jq + 1];
    bias4.z = b_ih[layer * HID + jq + 2] + b_hh[layer * HID + jq + 2];
    bias4.w = b_ih[layer * HID + jq + 3] + b_hh[layer * HID + jq + 3];
  }

  // ---- initial emb prefetch (t=0, l0) ----
  float4 pf[4];
  if (layer == 0) {
    #pragma unroll
    for (int i = 0; i < 4; ++i) {
      const int u = tid + NTHR * i;
      const int r = u >> 7, c = (u & 127) * 4;
      const int tok = x[(bbase + r) * SEQ];
      pf[i] = *(const float4*)&emb[(size_t)tok * HID + c];
    }
  }

  int cur = 0, prev = ring - 1;   // p % ring, (p-1) % ring

  for (int p = 0; p <= P; ++p) {
    const bool active = layer ? (p >= 1) : (p < SEQ);
    const int  wr0    = (cur + 1 == ring) ? 0 : (cur + 1);

    if (active) {
      const int t = layer ? (p - 1) : p;

      // ---- stage: sc1 ring loads -> LDS (NP: data poll IS the sync) ----
      if (layer == 0) {
        const double* src = (const double*)(h0r) + (size_t)cur * (SLOT / 2);
        if constexpr (NP) {
          u64 tv[8];
          #pragma unroll
          for (int i = 0; i < 8; ++i) {
            const int u = tid + NTHR * i;
            tv[i] = ldu(&src[(size_t)(bbase + (u >> 8)) * 256 + (u & 255)]);
          }
          for (;;) {
            u32 bad = 0;
            #pragma unroll
            for (int i = 0; i < 8; ++i) bad |= (tv[i] == POISON) ? (1u << i) : 0u;
            if (!bad) break;
            #pragma unroll
            for (int i = 0; i < 8; ++i)
              if (bad & (1u << i)) {
                const int u = tid + NTHR * i;
                tv[i] = ldu(&src[(size_t)(bbase + (u >> 8)) * 256 + (u & 255)]);
              }
          }
          #pragma unroll
          for (int i = 0; i < 8; ++i) {
            const int u = tid + NTHR * i;
            *(float2*)&Xb[u >> 8][(u & 255) * 2] = __builtin_bit_cast(float2, tv[i]);
          }
        } else {
          float2 tv[8];
          #pragma unroll
          for (int i = 0; i < 8; ++i) {
            const int u = tid + NTHR * i;
            tv[i] = ld2(&src[(size_t)(bbase + (u >> 8)) * 256 + (u & 255)]);
          }
          #pragma unroll
          for (int i = 0; i < 8; ++i) {
            const int u = tid + NTHR * i;
            *(float2*)&Xb[u >> 8][(u & 255) * 2] = tv[i];
          }
        }
        #pragma unroll
        for (int i = 0; i < 4; ++i) {
          const int u = tid + NTHR * i;
          *(float4*)&Xa[u >> 7][(u & 127) * 4] = pf[i];
        }
      } else {
        const double* srcB = (const double*)(h1r) + (size_t)prev * (SLOT / 2);
        const double* srcA = (const double*)(h0r) + (size_t)cur  * (SLOT / 2);
        if constexpr (NP) {
          u64 tb[8], ta[8];
          #pragma unroll                       // critical (h1 self-chain) first
          for (int i = 0; i < 8; ++i) {
            const int u = tid + NTHR * i;
            tb[i] = ldu(&srcB[(size_t)(bbase + (u >> 8)) * 256 + (u & 255)]);
          }
          #pragma unroll
          for (int i = 0; i < 8; ++i) {
            const int u = tid + NTHR * i;
            ta[i] = ldu(&srcA[(size_t)(bbase + (u >> 8)) * 256 + (u & 255)]);
          }
          for (;;) {
            u32 bad = 0;
            #pragma unroll
            for (int i = 0; i < 8; ++i) {
              bad |= (tb[i] == POISON) ? (1u << i) : 0u;
              bad |= (ta[i] == POISON) ? (1u << (i + 8)) : 0u;
            }
            if (!bad) break;
            #pragma unroll
            for (int i = 0; i < 8; ++i) {
              const int u = tid + NTHR * i;
              if (bad & (1u << i))
                tb[i] = ldu(&srcB[(size_t)(bbase + (u >> 8)) * 256 + (u & 255)]);
              if (bad & (1u << (i + 8)))
                ta[i] = ldu(&srcA[(size_t)(bbase + (u >> 8)) * 256 + (u & 255)]);
            }
          }
          #pragma unroll
          for (int i = 0; i < 8; ++i) {
            const int u = tid + NTHR * i;
            *(float2*)&Xb[u >> 8][(u & 255) * 2] = __builtin_bit_cast(float2, tb[i]);
            *(float2*)&Xa[u >> 8][(u & 255) * 2] = __builtin_bit_cast(float2, ta[i]);
          }
        } else {
          float2 tb[8], ta[8];
          #pragma unroll
          for (int i = 0; i < 8; ++i) {
            const int u = tid + NTHR * i;
            tb[i] = ld2(&srcB[(size_t)(bbase + (u >> 8)) * 256 + (u & 255)]);
          }
          #pragma unroll
          for (int i = 0; i < 8; ++i) {
            const int u = tid + NTHR * i;
            ta[i] = ld2(&srcA[(size_t)(bbase + (u >> 8)) * 256 + (u & 255)]);
          }
          #pragma unroll
          for (int i = 0; i < 8; ++i) {
            const int u = tid + NTHR * i;
            *(float2*)&Xb[u >> 8][(u & 255) * 2] = tb[i];
            *(float2*)&Xa[u >> 8][(u & 255) * 2] = ta[i];
          }
        }
      }
      __syncthreads();

      // ---- compute: 4 groups, unroll 2; skip fully-frozen groups ----
      #pragma unroll 2
      for (int g = 0; g < 4; ++g) {
        if (t >= lm[g]) continue;            // wave-uniform (Lens shared)
        float v[16];
        #pragma unroll
        for (int o = 0; o < 16; ++o) v[o] = 0.f;
        #pragma unroll
        for (int bi = 0; bi < 2; ++bi) {
          const int b = g * 2 + bi;
          const float4 xa0 = *(const float4*)&Xa[b][4 * lane];
          const float4 xa1 = *(const float4*)&Xa[b][256 + 4 * lane];
          const float4 xb0 = *(const float4*)&Xb[b][4 * lane];
          const float4 xb1 = *(const float4*)&Xb[b][256 + 4 * lane];
          #pragma unroll
          for (int ji = 0; ji < 8; ++ji) {
            v[bi * 8 + ji] += dot4(wa[0][ji], xa0) + dot4(wa[1][ji], xa1)
                            + dot4(wb[0][ji], xb0) + dot4(wb[1][ji], xb1);
          }
        }
        RSTEP(32, 8)
        RSTEP(16, 4)
        RSTEP(8, 2)
        RSTEP(4, 1)
        const int b_o = g * 2 + (lane >> 5);
        const int j_o = tj * 8 + ((lane >> 2) & 7);
        Xpart[b_o][j_o][lane & 3] = v[0];
      }
      __syncthreads();

      // ---- finalize: sum partials, fast tanh, mask, sc1 ring store ----
      if (tid < 64) {
        const int b = tid >> 3, jq = (tid & 7) * 4;
        const float4 hb = *(const float4*)&Xb[b][jbase + jq];
        const bool live = (t < Lens[b]);
        float4 r = hb;
        if (live) {
          const float4 p0 = *(const float4*)&Xpart[b][jq + 0][0];
          const float4 p1 = *(const float4*)&Xpart[b][jq + 1][0];
          const float4 p2 = *(const float4*)&Xpart[b][jq + 2][0];
          const float4 p3 = *(const float4*)&Xpart[b][jq + 3][0];
          r.x = tanh_fast(p0.x + p0.y + p0.z + p0.w + bias4.x);
          r.y = tanh_fast(p1.x + p1.y + p1.z + p1.w + bias4.y);
          r.z = tanh_fast(p2.x + p2.y + p2.z + p2.w + bias4.z);
          r.w = tanh_fast(p3.x + p3.y + p3.z + p3.w + bias4.w);
        }
        double* dst = layer ? ((double*)h1r + (size_t)cur * (SLOT / 2))
                            : ((double*)h0r + (size_t)wr0 * (SLOT / 2));
        const size_t di = (size_t)(bbase + b) * 256 + ((jbase + jq) >> 1);
        st2(&dst[di],     make_float2(r.x, r.y));
        st2(&dst[di + 1], make_float2(r.z, r.w));
        if (p == plast) {   // fused epilogue: own tile = own output
          if (layer == 0) {
            *(float4*)&out[32768 + (size_t)(bbase + b) * 1024 + jbase + jq] = r;
          } else {
            *(float4*)&out[(size_t)(bbase + b) * 512 + jbase + jq] = r;
            *(float4*)&out[32768 + (size_t)(bbase + b) * 1024 + 512 + jbase + jq] = r;
          }
        }
      }
    }

    if constexpr (NP) {
      // ---- no flags, no drain: stores self-announce via non-poison data ----
      const int np = p + 1;
      if (layer == 0 && np <= plast) {
        #pragma unroll
        for (int i = 0; i < 4; ++i) {
          const int u = tid + NTHR * i;
          const int r = u >> 7, c = (u & 127) * 4;
          const int tok = x[(bbase + r) * SEQ + np];
          pf[i] = *(const float4*)&emb[(size_t)tok * HID + c];
        }
      }
      __syncthreads();   // protect Xa/Xb/Xpart before next stage overwrite
    } else {
      // ---- R10 fallback: drain -> flag store -> prefetch -> detect ----
      WAIT_VM0();
      __syncthreads();
      if (tid == 0 && active)   // l0 publishes p+1 slots, l1 publishes p
        __hip_atomic_store(Fown, (u32)(layer ? p : (p + 1)),
                           __ATOMIC_RELAXED, __HIP_MEMORY_SCOPE_AGENT);
      const int np = p + 1;
      if (layer == 0 && np <= plast) {
        #pragma unroll
        for (int i = 0; i < 4; ++i) {
          const int u = tid + NTHR * i;
          const int r = u >> 7, c = (u & 127) * 4;
          const int tok = x[(bbase + r) * SEQ + np];
          pf[i] = *(const float4*)&emb[(size_t)tok * HID + c];
        }
      }
      if (np <= P) {
        if (tid < 64) {
          u32* fp  = Fown;            // dummy for idle lanes (always valid)
          u32  tgt = 0;
          bool idle = true;
          if (lane < 16) { fp = F0 + lane * 32; tgt = (u32)np; idle = false; }
          else if (lane < 32) {
            if (layer) { fp = F1 + (lane - 16) * 32; tgt = (u32)(np - 1); idle = false; }
            else {
              const int th = np + 1 - ring;   // small-ring WAR throttle
              if (th > 0) { fp = F1 + (lane - 16) * 32; tgt = (u32)th; idle = false; }
            }
          }
          while (true) {
            const u32 vv = __hip_atomic_load(fp, __ATOMIC_RELAXED,
                                             __HIP_MEMORY_SCOPE_AGENT);
            const bool ok = idle || (vv >= tgt);
            if (__ballot(ok) == ~0ull) break;
          }
        }
        __syncthreads();
      }
    }
    prev = cur; cur = wr0;
  }
}

extern "C" void kernel_launch(void* const* d_in, const int* in_sizes, int n_in,
                              void* d_out, int out_size, void* d_ws, size_t ws_size,
                              hipStream_t stream) {
  (void)in_sizes; (void)n_in; (void)out_size;
  const int*   x       = (const int*)d_in[0];
  const int*   lengths = (const int*)d_in[1];
  const float* emb     = (const float*)d_in[2];
  const float* W_ih    = (const float*)d_in[3];
  const float* W_hh    = (const float*)d_in[4];
  const float* b_ih    = (const float*)d_in[5];
  const float* b_hh    = (const float*)d_in[6];
  float* out = (float*)d_out;

  const size_t slotB = (size_t)SLOT * sizeof(float);            // 128KB
  const size_t needFull = 2 * (size_t)513 * slotB + 65536;      // ~131.5MB
  const int ring = (ws_size >= needFull) ? 513 : 17;            // 17: throttled

  float* h0r = (float*)d_ws;
  float* h1r = h0r + (size_t)ring * SLOT;
  u32*   F   = (u32*)(h1r + (size_t)ring * SLOT);

  if (ring == 513) {
    // NaN-poll protocol: poison BOTH rings (pattern the kernel never stores),
    // then zero slot 0 of each (h(-1)=0). Same-stream order guarantees this.
    hipMemsetAsync(h0r, 0xFF, 2 * (size_t)513 * slotB, stream);
    hipMemsetAsync(h0r, 0, slotB, stream);
    hipMemsetAsync(h1r, 0, slotB, stream);
    hipLaunchKernelGGL((rnn_persistent<true>), dim3(256), dim3(NTHR), 0, stream,
                       x, lengths, emb, W_ih, W_hh, b_ih, b_hh, out,
                       h0r, h1r, F, ring);
  } else {
    // R10 flag protocol fallback (small ring, WAR-throttled)
    hipMemsetAsync(h0r, 0, slotB, stream);
    hipMemsetAsync(h1r, 0, slotB, stream);
    hipMemsetAsync(F, 0, 32768, stream);
    hipLaunchKernelGGL((rnn_persistent<false>), dim3(256), dim3(NTHR), 0, stream,
                       x, lengths, emb, W_ih, W_hh, b_ih, b_hh, out,
                       h0r, h1r, F, ring);
  }
}